// Round 1
// baseline (1290.568 us; speedup 1.0000x reference)
//
#include <hip/hip_runtime.h>
#include <hip/hip_bf16.h>

// MambaStateSpaceLayer: B=2, S=1024, D_MODEL=1024, D_STATE=16, D_INNER=2048
// Round 0: correct fp32 baseline.
//   GEMM1: gate = sigmoid(x @ W_gate^T + b_gate)          [2048,2048]
//   GEMM2: proj = x @ W_in^T + b_in -> x_proj | relu=delta [2048,2048]x2
//   Scan : z = gate * (selective_scan(x_proj, delta) )     (z overwrites gate)
//   GEMM3: out = z @ W_out^T + b_out                       [2048,1024]

#define LOG2E 1.4426950408889634f

constexpr int TILE = 128;
constexpr int BK = 16;

__device__ __forceinline__ float fexp2(float x) { return __builtin_amdgcn_exp2f(x); }

// C = A[M,K] @ W[N,K]^T + bias, row-major everything, all dims multiples of TILE/BK.
// MODE 0: sigmoid -> C (ldc = gridDim.x*TILE)
// MODE 1: n <  Nhalf : identity -> C  [m*Nhalf + n]
//         n >= Nhalf : relu     -> C2 [m*Nhalf + n-Nhalf]
// MODE 2: identity -> C (ldc = gridDim.x*TILE)
template <int MODE>
__global__ __launch_bounds__(256, 2) void gemm_xwt(
    const float* __restrict__ A,
    const float* __restrict__ W,
    const float* __restrict__ bias,
    float* __restrict__ C,
    float* __restrict__ C2,
    int K, int Nhalf)
{
    __shared__ __align__(16) float As[BK][TILE];
    __shared__ __align__(16) float Ws[BK][TILE];

    const int tid = threadIdx.x;
    const int tx = tid & 15;          // n-thread 0..15 (8 cols each)
    const int ty = tid >> 4;          // m-thread 0..15 (8 rows each)
    const int mbase = blockIdx.y * TILE;
    const int nbase = blockIdx.x * TILE;

    // loader mapping: tid -> (row 0..63, 4-col group), second chunk adds 64 rows
    const int lrow = tid >> 2;        // 0..63
    const int lc4 = (tid & 3) * 4;    // 0,4,8,12

    const float* Ap = A + (size_t)(mbase + lrow) * K + lc4;
    const float* Wp = W + (size_t)(nbase + lrow) * K + lc4;
    const size_t halfOff = (size_t)64 * K;

    float acc[8][8];
    #pragma unroll
    for (int i = 0; i < 8; ++i)
        #pragma unroll
        for (int j = 0; j < 8; ++j) acc[i][j] = 0.0f;

    for (int k0 = 0; k0 < K; k0 += BK) {
        const float4 a0 = *(const float4*)(Ap + k0);
        const float4 a1 = *(const float4*)(Ap + halfOff + k0);
        const float4 w0 = *(const float4*)(Wp + k0);
        const float4 w1 = *(const float4*)(Wp + halfOff + k0);
        __syncthreads();   // previous iteration's reads done before overwrite
        As[lc4 + 0][lrow] = a0.x; As[lc4 + 1][lrow] = a0.y;
        As[lc4 + 2][lrow] = a0.z; As[lc4 + 3][lrow] = a0.w;
        As[lc4 + 0][lrow + 64] = a1.x; As[lc4 + 1][lrow + 64] = a1.y;
        As[lc4 + 2][lrow + 64] = a1.z; As[lc4 + 3][lrow + 64] = a1.w;
        Ws[lc4 + 0][lrow] = w0.x; Ws[lc4 + 1][lrow] = w0.y;
        Ws[lc4 + 2][lrow] = w0.z; Ws[lc4 + 3][lrow] = w0.w;
        Ws[lc4 + 0][lrow + 64] = w1.x; Ws[lc4 + 1][lrow + 64] = w1.y;
        Ws[lc4 + 2][lrow + 64] = w1.z; Ws[lc4 + 3][lrow + 64] = w1.w;
        __syncthreads();

        #pragma unroll
        for (int k = 0; k < BK; ++k) {
            const float4 fa0 = *(const float4*)&As[k][ty * 8];
            const float4 fa1 = *(const float4*)&As[k][ty * 8 + 4];
            const float4 fb0 = *(const float4*)&Ws[k][tx * 8];
            const float4 fb1 = *(const float4*)&Ws[k][tx * 8 + 4];
            const float av[8] = {fa0.x, fa0.y, fa0.z, fa0.w, fa1.x, fa1.y, fa1.z, fa1.w};
            const float bv[8] = {fb0.x, fb0.y, fb0.z, fb0.w, fb1.x, fb1.y, fb1.z, fb1.w};
            #pragma unroll
            for (int i = 0; i < 8; ++i)
                #pragma unroll
                for (int j = 0; j < 8; ++j)
                    acc[i][j] = fmaf(av[i], bv[j], acc[i][j]);
        }
    }

    const int ncol = nbase + tx * 8;
    float bb[8];
    #pragma unroll
    for (int j = 0; j < 8; ++j) bb[j] = bias[ncol + j];

    #pragma unroll
    for (int i = 0; i < 8; ++i) {
        const int m = mbase + ty * 8 + i;
        float o[8];
        #pragma unroll
        for (int j = 0; j < 8; ++j) {
            float v = acc[i][j] + bb[j];
            if (MODE == 0) v = 1.0f / (1.0f + fexp2(-v * LOG2E));
            o[j] = v;
        }
        if (MODE == 1) {
            if (nbase >= Nhalf) {
                #pragma unroll
                for (int j = 0; j < 8; ++j) o[j] = fmaxf(o[j], 0.0f);
                float* dst = C2 + (size_t)m * Nhalf + (ncol - Nhalf);
                *(float4*)dst = make_float4(o[0], o[1], o[2], o[3]);
                *(float4*)(dst + 4) = make_float4(o[4], o[5], o[6], o[7]);
            } else {
                float* dst = C + (size_t)m * Nhalf + ncol;
                *(float4*)dst = make_float4(o[0], o[1], o[2], o[3]);
                *(float4*)(dst + 4) = make_float4(o[4], o[5], o[6], o[7]);
            }
        } else {
            const int N = gridDim.x * TILE;
            float* dst = C + (size_t)m * N + ncol;
            *(float4*)dst = make_float4(o[0], o[1], o[2], o[3]);
            *(float4*)(dst + 4) = make_float4(o[4], o[5], o[6], o[7]);
        }
    }
}

// One thread per (b, d) channel; 16 states in registers; sequential over S=1024.
// gz holds gate on input, z = gate*(y + x*D) on output (in place).
__global__ __launch_bounds__(256) void mamba_scan(
    const float* __restrict__ xproj,
    const float* __restrict__ delta,
    const float* __restrict__ A_log,
    const float* __restrict__ B_mat,
    const float* __restrict__ C_mat,
    const float* __restrict__ D_vec,
    float* __restrict__ gz)
{
    const int gid = blockIdx.x * blockDim.x + threadIdx.x;  // 0..4095
    const int d = gid & 2047;
    const int b = gid >> 11;

    float Ac[16], Bv[16], Cv[16];
    #pragma unroll
    for (int s = 0; s < 16; ++s) {
        // A = -exp(A_log); exp(A*dt) = exp2((A*log2e)*dt)
        Ac[s] = -fexp2(A_log[d * 16 + s] * LOG2E) * LOG2E;
        Bv[s] = B_mat[d * 16 + s];
        Cv[s] = C_mat[s];               // c0 = C_mat row 0
    }
    const float Dv = D_vec[d];

    float h[16];
    #pragma unroll
    for (int s = 0; s < 16; ++s) h[s] = 0.0f;

    size_t idx = (size_t)b * 1024 * 2048 + d;
    for (int t = 0; t < 1024; ++t, idx += 2048) {
        const float xt = xproj[idx];
        const float dt = delta[idx];
        const float g = gz[idx];
        const float xdt = xt * dt;
        float y = 0.0f;
        #pragma unroll
        for (int s = 0; s < 16; ++s) {
            h[s] = fmaf(h[s], fexp2(Ac[s] * dt), xdt * Bv[s]);
            y = fmaf(h[s], Cv[s], y);
        }
        gz[idx] = g * (y + xt * Dv);
    }
}

extern "C" void kernel_launch(void* const* d_in, const int* in_sizes, int n_in,
                              void* d_out, int out_size, void* d_ws, size_t ws_size,
                              hipStream_t stream) {
    const float* x      = (const float*)d_in[0];   // [2,1024,1024]
    const float* W_in   = (const float*)d_in[1];   // [4096,1024]
    const float* b_in   = (const float*)d_in[2];   // [4096]
    const float* W_gate = (const float*)d_in[3];   // [2048,1024]
    const float* b_gate = (const float*)d_in[4];   // [2048]
    const float* W_out  = (const float*)d_in[5];   // [1024,2048]
    const float* b_out  = (const float*)d_in[6];   // [1024]
    const float* A_log  = (const float*)d_in[7];   // [2048,16]
    const float* B_mat  = (const float*)d_in[8];   // [2048,16]
    const float* C_mat  = (const float*)d_in[9];   // [2048,16] (row 0 used)
    const float* D_vec  = (const float*)d_in[10];  // [2048]
    float* out = (float*)d_out;                    // [2,1024,1024]

    float* ws = (float*)d_ws;
    const size_t TOK = 2048, DI = 2048;
    float* gate_z = ws;                        // [2048,2048]; becomes z in-place
    float* xproj  = ws + TOK * DI;             // [2048,2048]
    float* deltab = ws + 2 * TOK * DI;         // [2048,2048]

    dim3 blk(256);
    // gate = sigmoid(x @ W_gate^T + b_gate): M=2048, N=2048, K=1024
    gemm_xwt<0><<<dim3(16, 16), blk, 0, stream>>>(x, W_gate, b_gate, gate_z, nullptr, 1024, 0);
    // proj = x @ W_in^T + b_in -> xproj | relu delta: N=4096
    gemm_xwt<1><<<dim3(32, 16), blk, 0, stream>>>(x, W_in, b_in, xproj, deltab, 1024, 2048);
    // selective scan fused with gate multiply (z overwrites gate)
    mamba_scan<<<dim3(16), blk, 0, stream>>>(xproj, deltab, A_log, B_mat, C_mat, D_vec, gate_z);
    // out = z @ W_out^T + b_out: M=2048, N=1024, K=2048
    gemm_xwt<2><<<dim3(8, 16), blk, 0, stream>>>(gate_z, W_out, b_out, out, nullptr, 2048, 0);
}

// Round 2
// 260.461 us; speedup vs baseline: 4.9549x; 4.9549x over previous
//
#include <hip/hip_runtime.h>
#include <hip/hip_bf16.h>

// MambaStateSpaceLayer: B=2, S=1024, D_MODEL=1024, D_STATE=16, D_INNER=2048
// Round 2: bf16 MFMA GEMMs + 3-phase chunked parallel scan.

#define LOG2E 1.4426950408889634f

typedef float floatx4 __attribute__((ext_vector_type(4)));
typedef short short8 __attribute__((ext_vector_type(8)));

__device__ __forceinline__ float fexp2(float x) { return __builtin_amdgcn_exp2f(x); }
__device__ __forceinline__ unsigned short f2bf(float f) {
    unsigned int u = __float_as_uint(f);
    u = (u + 0x7fffu + ((u >> 16) & 1u)) >> 16;   // round-to-nearest-even
    return (unsigned short)u;
}
__device__ __forceinline__ float bf2f(unsigned short h) {
    return __uint_as_float(((unsigned int)h) << 16);
}

// ---------------- cast x, W_gate, W_in, W_out to bf16 (one kernel) -----------
__global__ __launch_bounds__(256) void cast_to_bf16(
    const float* __restrict__ x, const float* __restrict__ wg,
    const float* __restrict__ wi, const float* __restrict__ wo,
    unsigned short* __restrict__ ox, unsigned short* __restrict__ owg,
    unsigned short* __restrict__ owi, unsigned short* __restrict__ owo)
{
    const size_t e = ((size_t)blockIdx.x * 256 + threadIdx.x) * 4;
    const float* src; unsigned short* dst; size_t off;
    if (e < 2097152)      { src = x;  dst = ox;  off = e; }
    else if (e < 4194304) { src = wg; dst = owg; off = e - 2097152; }
    else if (e < 8388608) { src = wi; dst = owi; off = e - 4194304; }
    else                  { src = wo; dst = owo; off = e - 8388608; }
    float4 v = *(const float4*)(src + off);
    *(ushort4*)(dst + off) = make_ushort4(f2bf(v.x), f2bf(v.y), f2bf(v.z), f2bf(v.w));
}

// ---------------- bf16 MFMA GEMM: C = A[M,K] @ W[N,K]^T + bias ---------------
// 128x128 tile, 4 waves (2x2 of 64x64), BK=32, LDS rows padded to 40 elems.
// MODE 0: sigmoid -> bf16 C (ld = N)
// MODE 1: n < Nhalf -> f32 C ; n >= Nhalf -> relu -> f32 C2 (ld = Nhalf each)
// MODE 2: f32 C (ld = N)
constexpr int GT = 128;
constexpr int GBK = 32;
constexpr int LDSW = 40;   // 80B row stride: 16B-aligned, 2-way-bank (free)

template <int MODE>
__global__ __launch_bounds__(256) void gemm_bf16(
    const unsigned short* __restrict__ A, const unsigned short* __restrict__ W,
    const float* __restrict__ bias,
    void* __restrict__ Cout, float* __restrict__ C2,
    int K, int N, int Nhalf)
{
    __shared__ short As[GT * LDSW];
    __shared__ short Ws[GT * LDSW];
    const int tid = threadIdx.x;
    const int mbase = blockIdx.y * GT;
    const int nbase = blockIdx.x * GT;

    // staging: each thread loads 16 bf16 of A and of W
    const int lrow = tid >> 1;           // 0..127
    const int lhal = (tid & 1) * 16;     // 0 or 16
    const unsigned short* Ap = A + (size_t)(mbase + lrow) * K + lhal;
    const unsigned short* Wp = W + (size_t)(nbase + lrow) * K + lhal;
    short* asd = &As[lrow * LDSW + lhal];
    short* wsd = &Ws[lrow * LDSW + lhal];

    // MFMA fragment mapping (gfx950 16x16x32 bf16):
    //   A: row = lane&15, k = (lane>>4)*8 + b ;  B: col = lane&15, same k
    //   D: col = lane&15, row = (lane>>4)*4 + reg
    const int l = tid & 63;
    const int w = tid >> 6;
    const int wm = (w >> 1) * 64, wn = (w & 1) * 64;
    const int frow = l & 15, fk = (l >> 4) * 8;

    floatx4 acc[4][4] = {};
    for (int k0 = 0; k0 < K; k0 += GBK) {
        short8 a0 = *(const short8*)(Ap + k0);
        short8 a1 = *(const short8*)(Ap + k0 + 8);
        short8 w0 = *(const short8*)(Wp + k0);
        short8 w1 = *(const short8*)(Wp + k0 + 8);
        __syncthreads();
        *(short8*)(asd) = a0; *(short8*)(asd + 8) = a1;
        *(short8*)(wsd) = w0; *(short8*)(wsd + 8) = w1;
        __syncthreads();
        short8 af[4], bfr[4];
        #pragma unroll
        for (int i = 0; i < 4; ++i) {
            af[i]  = *(const short8*)&As[(wm + i * 16 + frow) * LDSW + fk];
            bfr[i] = *(const short8*)&Ws[(wn + i * 16 + frow) * LDSW + fk];
        }
        #pragma unroll
        for (int i = 0; i < 4; ++i)
            #pragma unroll
            for (int j = 0; j < 4; ++j)
                acc[i][j] = __builtin_amdgcn_mfma_f32_16x16x32_bf16(af[i], bfr[j], acc[i][j], 0, 0, 0);
    }

    const int crow = wm + (l >> 4) * 4;
    const int ccol = wn + (l & 15);
    #pragma unroll
    for (int j = 0; j < 4; ++j) {
        const int n = nbase + ccol + j * 16;
        const float bb = bias[n];
        #pragma unroll
        for (int i = 0; i < 4; ++i) {
            const int mrow = mbase + crow + i * 16;
            #pragma unroll
            for (int r = 0; r < 4; ++r) {
                float v = acc[i][j][r] + bb;
                const int m = mrow + r;
                if (MODE == 0) {
                    float s = 1.0f / (1.0f + fexp2(-v * LOG2E));
                    ((unsigned short*)Cout)[(size_t)m * N + n] = f2bf(s);
                } else if (MODE == 1) {
                    if (n < Nhalf) ((float*)Cout)[(size_t)m * Nhalf + n] = v;
                    else           C2[(size_t)m * Nhalf + (n - Nhalf)] = fmaxf(v, 0.0f);
                } else {
                    ((float*)Cout)[(size_t)m * N + n] = v;
                }
            }
        }
    }
}

// ---------------- chunked selective scan ------------------------------------
// h[t] = h[t-1]*exp(A*dt[t]) + x[t]*dt[t]*B ; y = h @ C_row0
// Split S=1024 into NC=32 chunks of CL=32. Linear recurrence superposition:
//   h_end(chunk) = h_start * exp(A*sum(dt)) + Q(local scan from 0)
constexpr int NC = 32, CL = 32;

__global__ __launch_bounds__(256) void scan_phaseA(
    const float* __restrict__ xp, const float* __restrict__ dl,
    const float* __restrict__ A_log, const float* __restrict__ B_mat,
    float* __restrict__ Q, float* __restrict__ sumdt)
{
    const int ch = blockIdx.x * 256 + threadIdx.x;   // 0..4095
    const int c = blockIdx.y;                         // 0..NC-1
    const int d = ch & 2047, b = ch >> 11;
    float Ac[16], Bv[16], h[16];
    #pragma unroll
    for (int s = 0; s < 16; ++s) {
        Ac[s] = -fexp2(A_log[d * 16 + s] * LOG2E) * LOG2E;
        Bv[s] = B_mat[d * 16 + s];
        h[s] = 0.0f;
    }
    float sd = 0.0f;
    size_t idx = ((size_t)b * 1024 + (size_t)c * CL) * 2048 + d;
    for (int t = 0; t < CL; ++t, idx += 2048) {
        const float xt = xp[idx], dt = dl[idx];
        sd += dt;
        const float xdt = xt * dt;
        #pragma unroll
        for (int s = 0; s < 16; ++s)
            h[s] = fmaf(h[s], fexp2(Ac[s] * dt), xdt * Bv[s]);
    }
    float* q = Q + ((size_t)ch * NC + c) * 16;
    #pragma unroll
    for (int s = 0; s < 16; ++s) q[s] = h[s];
    sumdt[ch * NC + c] = sd;
}

__global__ __launch_bounds__(256) void scan_phaseB(
    const float* __restrict__ A_log, const float* __restrict__ Q,
    const float* __restrict__ sumdt, float* __restrict__ hst)
{
    const int s = threadIdx.x & 15;
    const int ch = blockIdx.x * 16 + (threadIdx.x >> 4);  // grid = 256
    const int d = ch & 2047;
    const float Ac = -fexp2(A_log[d * 16 + s] * LOG2E) * LOG2E;
    float h = 0.0f;
    const float* q = Q + (size_t)ch * NC * 16 + s;
    const float* sd = sumdt + ch * NC;
    float* hs = hst + (size_t)ch * NC * 16 + s;
    for (int c = 0; c < NC; ++c) {
        hs[c * 16] = h;                       // state entering chunk c
        h = fmaf(h, fexp2(Ac * sd[c]), q[c * 16]);
    }
}

__global__ __launch_bounds__(256) void scan_phaseC(
    const float* __restrict__ xp, const float* __restrict__ dl,
    const float* __restrict__ A_log, const float* __restrict__ B_mat,
    const float* __restrict__ C_mat, const float* __restrict__ D_vec,
    const unsigned short* __restrict__ gate, const float* __restrict__ hst,
    unsigned short* __restrict__ z)
{
    const int ch = blockIdx.x * 256 + threadIdx.x;
    const int c = blockIdx.y;
    const int d = ch & 2047, b = ch >> 11;
    float Ac[16], Bv[16], Cv[16], h[16];
    #pragma unroll
    for (int s = 0; s < 16; ++s) {
        Ac[s] = -fexp2(A_log[d * 16 + s] * LOG2E) * LOG2E;
        Bv[s] = B_mat[d * 16 + s];
        Cv[s] = C_mat[s];                     // c0 = C_mat row 0
        h[s] = hst[((size_t)ch * NC + c) * 16 + s];
    }
    const float Dv = D_vec[d];
    size_t idx = ((size_t)b * 1024 + (size_t)c * CL) * 2048 + d;
    for (int t = 0; t < CL; ++t, idx += 2048) {
        const float xt = xp[idx], dt = dl[idx];
        const float xdt = xt * dt;
        float y = 0.0f;
        #pragma unroll
        for (int s = 0; s < 16; ++s) {
            h[s] = fmaf(h[s], fexp2(Ac[s] * dt), xdt * Bv[s]);
            y = fmaf(h[s], Cv[s], y);
        }
        const float g = bf2f(gate[idx]);
        z[idx] = f2bf(g * (y + xt * Dv));
    }
}

// ---------------------------------------------------------------------------
extern "C" void kernel_launch(void* const* d_in, const int* in_sizes, int n_in,
                              void* d_out, int out_size, void* d_ws, size_t ws_size,
                              hipStream_t stream) {
    const float* x      = (const float*)d_in[0];
    const float* W_in   = (const float*)d_in[1];
    const float* b_in   = (const float*)d_in[2];
    const float* W_gate = (const float*)d_in[3];
    const float* b_gate = (const float*)d_in[4];
    const float* W_out  = (const float*)d_in[5];
    const float* b_out  = (const float*)d_in[6];
    const float* A_log  = (const float*)d_in[7];
    const float* B_mat  = (const float*)d_in[8];
    const float* C_mat  = (const float*)d_in[9];
    const float* D_vec  = (const float*)d_in[10];
    float* out = (float*)d_out;

    // workspace layout
    float* fws = (float*)d_ws;
    float* xproj = fws;                         //  4,194,304 f32
    float* delta = xproj + 4194304;             //  4,194,304 f32
    float* Q     = delta + 4194304;             //  2,097,152 f32 (4096*32*16)
    float* hst   = Q + 2097152;                 //  2,097,152 f32
    float* sumdt = hst + 2097152;               //    131,072 f32
    unsigned short* us = (unsigned short*)(sumdt + 131072);
    unsigned short* gate  = us;                 //  4,194,304 bf16
    unsigned short* z     = gate + 4194304;     //  4,194,304 bf16
    unsigned short* x_bf  = z + 4194304;        //  2,097,152 bf16
    unsigned short* wg_bf = x_bf + 2097152;     //  2,097,152 bf16
    unsigned short* wi_bf = wg_bf + 2097152;    //  4,194,304 bf16
    unsigned short* wo_bf = wi_bf + 4194304;    //  2,097,152 bf16
    // total ~88.6 MB

    dim3 blk(256);
    cast_to_bf16<<<10240, blk, 0, stream>>>(x, W_gate, W_in, W_out, x_bf, wg_bf, wi_bf, wo_bf);
    // gate = sigmoid(x @ W_gate^T + b_gate): M=2048,N=2048,K=1024 -> bf16
    gemm_bf16<0><<<dim3(16, 16), blk, 0, stream>>>(x_bf, wg_bf, b_gate, gate, nullptr, 1024, 2048, 0);
    // proj = x @ W_in^T + b_in: N=4096 -> xproj | relu -> delta (f32)
    gemm_bf16<1><<<dim3(32, 16), blk, 0, stream>>>(x_bf, wi_bf, b_in, xproj, delta, 1024, 4096, 2048);
    // chunked selective scan, fused gate*(y + x*D) -> z (bf16)
    scan_phaseA<<<dim3(16, NC), blk, 0, stream>>>(xproj, delta, A_log, B_mat, Q, sumdt);
    scan_phaseB<<<256, blk, 0, stream>>>(A_log, Q, sumdt, hst);
    scan_phaseC<<<dim3(16, NC), blk, 0, stream>>>(xproj, delta, A_log, B_mat, C_mat, D_vec, gate, hst, z);
    // out = z @ W_out^T + b_out: M=2048,N=1024,K=2048 (f32 out)
    gemm_bf16<2><<<dim3(8, 16), blk, 0, stream>>>(z, wo_bf, b_out, out, nullptr, 2048, 1024, 0);
}

// Round 3
// 209.572 us; speedup vs baseline: 6.1581x; 1.2428x over previous
//
#include <hip/hip_runtime.h>
#include <hip/hip_bf16.h>

// MambaStateSpaceLayer: B=2, S=1024, D_MODEL=1024, D_STATE=16, D_INNER=2048
// Round 3: m97-structure GEMMs (global_load_lds w=16, BK=64, T2 XOR swizzle),
// fused gate+proj GEMM, 64x128 tile for the output GEMM. Scan unchanged.

#define LOG2E 1.4426950408889634f

typedef float floatx4 __attribute__((ext_vector_type(4)));
typedef short short8 __attribute__((ext_vector_type(8)));

__device__ __forceinline__ float fexp2(float x) { return __builtin_amdgcn_exp2f(x); }
__device__ __forceinline__ unsigned short f2bf(float f) {
    unsigned int u = __float_as_uint(f);
    u = (u + 0x7fffu + ((u >> 16) & 1u)) >> 16;   // round-to-nearest-even
    return (unsigned short)u;
}
__device__ __forceinline__ float bf2f(unsigned short h) {
    return __uint_as_float(((unsigned int)h) << 16);
}

// async 16B global -> LDS. lp MUST be wave-uniform (HW adds lane*16).
#define GLDS16(gp, lp) __builtin_amdgcn_global_load_lds(                      \
    (const __attribute__((address_space(1))) void*)(gp),                      \
    (__attribute__((address_space(3))) void*)(lp), 16, 0, 0)

// ---------------- cast x, W_gate, W_in, W_out to bf16 ------------------------
__global__ __launch_bounds__(256) void cast_to_bf16(
    const float* __restrict__ x, const float* __restrict__ wg,
    const float* __restrict__ wi, const float* __restrict__ wo,
    unsigned short* __restrict__ ox, unsigned short* __restrict__ owg,
    unsigned short* __restrict__ owi, unsigned short* __restrict__ owo)
{
    const size_t e = ((size_t)blockIdx.x * 256 + threadIdx.x) * 4;
    const float* src; unsigned short* dst; size_t off;
    if (e < 2097152)      { src = x;  dst = ox;  off = e; }
    else if (e < 4194304) { src = wg; dst = owg; off = e - 2097152; }
    else if (e < 8388608) { src = wi; dst = owi; off = e - 4194304; }
    else                  { src = wo; dst = owo; off = e - 8388608; }
    float4 v = *(const float4*)(src + off);
    *(ushort4*)(dst + off) = make_ushort4(f2bf(v.x), f2bf(v.y), f2bf(v.z), f2bf(v.w));
}

// ---------------- MFMA GEMM, m97 structure ----------------------------------
// C = A[M,K] @ W[N,K]^T + bias.  BK=64 bf16 (128B rows, 8x16B slots).
// Staging: global_load_lds dwordx4, linear LDS dest; source slot pre-swizzled
// (l&7)^(l>>3); ds_read uses slot ^ (row&7)  [rule #21: both-sides-or-neither].
// Block = 4 waves (2x2). Wave tile = (MI*16) x 64. BM = MI*32, BN = 128.
// MODE 3: fused input GEMM. blockIdx.x<16 -> gate=sigmoid->bf16 (W0,bias0);
//         else proj (W1,bias1): n<2048 -> xproj f32 ; n>=2048 -> relu delta f32.
// MODE 2: f32 out (N=1024).
template <int MODE, int MI>
__global__ __launch_bounds__(256, 2) void gemm_mfma(
    const unsigned short* __restrict__ A,
    const unsigned short* __restrict__ W0,
    const unsigned short* __restrict__ W1,
    const float* __restrict__ bias0, const float* __restrict__ bias1,
    unsigned short* __restrict__ gate,
    float* __restrict__ xproj, float* __restrict__ delta,
    float* __restrict__ outp, int K)
{
    constexpr int BM = MI * 32;
    constexpr int ROWA = BM / 32;          // A 1KB staging blocks per wave
    __shared__ short As[BM * 64];
    __shared__ short Bs[128 * 64];

    const int tid = threadIdx.x;
    const int l = tid & 63, w = tid >> 6;
    const int mbase = blockIdx.y * BM;

    const unsigned short* Wp; const float* bias; int nbase; bool isGate = false;
    if (MODE == 3) {
        const int bx = blockIdx.x;
        if (bx < 16) { Wp = W0; bias = bias0; nbase = bx * 128; isGate = true; }
        else         { Wp = W1; bias = bias1; nbase = (bx - 16) * 128; }
    } else { Wp = W0; bias = bias0; nbase = blockIdx.x * 128; }

    // per-lane staging source offsets (elements, k0 added per iter)
    const int rl = l >> 3;                 // row within 8-row block
    const int cs = (l & 7) ^ rl;           // inverse-swizzled source slot
    size_t aoff[ROWA], boff[4];
    #pragma unroll
    for (int j = 0; j < ROWA; ++j)
        aoff[j] = (size_t)(mbase + (w * ROWA + j) * 8 + rl) * K + cs * 8;
    #pragma unroll
    for (int j = 0; j < 4; ++j)
        boff[j] = (size_t)(nbase + (w * 4 + j) * 8 + rl) * K + cs * 8;

    const int wm = (w >> 1) * (MI * 16), wn = (w & 1) * 64;
    floatx4 acc[MI][4] = {};

    for (int k0 = 0; k0 < K; k0 += 64) {
        __syncthreads();                   // prior tile's ds_reads complete
        #pragma unroll
        for (int j = 0; j < ROWA; ++j)
            GLDS16(A + aoff[j] + k0, &As[(w * ROWA + j) * 512]);
        #pragma unroll
        for (int j = 0; j < 4; ++j)
            GLDS16(Wp + boff[j] + k0, &Bs[(w * 4 + j) * 512]);
        __syncthreads();                   // vmcnt(0) drained by compiler

        #pragma unroll
        for (int kk = 0; kk < 2; ++kk) {
            short8 af[MI], bfr[4];
            #pragma unroll
            for (int i = 0; i < MI; ++i) {
                const int row = wm + i * 16 + (l & 15);
                af[i] = *(const short8*)&As[row * 64 + (((kk * 4 + (l >> 4)) ^ (row & 7)) << 3)];
            }
            #pragma unroll
            for (int j = 0; j < 4; ++j) {
                const int row = wn + j * 16 + (l & 15);
                bfr[j] = *(const short8*)&Bs[row * 64 + (((kk * 4 + (l >> 4)) ^ (row & 7)) << 3)];
            }
            #pragma unroll
            for (int i = 0; i < MI; ++i)
                #pragma unroll
                for (int j = 0; j < 4; ++j)
                    acc[i][j] = __builtin_amdgcn_mfma_f32_16x16x32_bf16(af[i], bfr[j], acc[i][j], 0, 0, 0);
        }
    }

    // epilogue: D col = lane&15, row = (lane>>4)*4 + reg  [m89-verified]
    const int crow0 = wm + (l >> 4) * 4;
    const int ccol = wn + (l & 15);
    #pragma unroll
    for (int j = 0; j < 4; ++j) {
        const int n = nbase + ccol + j * 16;
        const float bb = bias[n];
        #pragma unroll
        for (int i = 0; i < MI; ++i) {
            const int mr = mbase + crow0 + i * 16;
            #pragma unroll
            for (int r = 0; r < 4; ++r) {
                const float v = acc[i][j][r] + bb;
                const int m = mr + r;
                if (MODE == 3) {
                    if (isGate) {
                        const float s = 1.0f / (1.0f + fexp2(-v * LOG2E));
                        gate[(size_t)m * 2048 + n] = f2bf(s);
                    } else if (n < 2048) {
                        xproj[(size_t)m * 2048 + n] = v;
                    } else {
                        delta[(size_t)m * 2048 + (n - 2048)] = fmaxf(v, 0.0f);
                    }
                } else {
                    outp[(size_t)m * 1024 + n] = v;
                }
            }
        }
    }
}

// ---------------- chunked selective scan (unchanged from round 2) ------------
constexpr int NC = 32, CL = 32;

__global__ __launch_bounds__(256) void scan_phaseA(
    const float* __restrict__ xp, const float* __restrict__ dl,
    const float* __restrict__ A_log, const float* __restrict__ B_mat,
    float* __restrict__ Q, float* __restrict__ sumdt)
{
    const int ch = blockIdx.x * 256 + threadIdx.x;
    const int c = blockIdx.y;
    const int d = ch & 2047, b = ch >> 11;
    float Ac[16], Bv[16], h[16];
    #pragma unroll
    for (int s = 0; s < 16; ++s) {
        Ac[s] = -fexp2(A_log[d * 16 + s] * LOG2E) * LOG2E;
        Bv[s] = B_mat[d * 16 + s];
        h[s] = 0.0f;
    }
    float sd = 0.0f;
    size_t idx = ((size_t)b * 1024 + (size_t)c * CL) * 2048 + d;
    for (int t = 0; t < CL; ++t, idx += 2048) {
        const float xt = xp[idx], dt = dl[idx];
        sd += dt;
        const float xdt = xt * dt;
        #pragma unroll
        for (int s = 0; s < 16; ++s)
            h[s] = fmaf(h[s], fexp2(Ac[s] * dt), xdt * Bv[s]);
    }
    float* q = Q + ((size_t)ch * NC + c) * 16;
    #pragma unroll
    for (int s = 0; s < 16; ++s) q[s] = h[s];
    sumdt[ch * NC + c] = sd;
}

__global__ __launch_bounds__(256) void scan_phaseB(
    const float* __restrict__ A_log, const float* __restrict__ Q,
    const float* __restrict__ sumdt, float* __restrict__ hst)
{
    const int s = threadIdx.x & 15;
    const int ch = blockIdx.x * 16 + (threadIdx.x >> 4);
    const int d = ch & 2047;
    const float Ac = -fexp2(A_log[d * 16 + s] * LOG2E) * LOG2E;
    float h = 0.0f;
    const float* q = Q + (size_t)ch * NC * 16 + s;
    const float* sd = sumdt + ch * NC;
    float* hs = hst + (size_t)ch * NC * 16 + s;
    for (int c = 0; c < NC; ++c) {
        hs[c * 16] = h;
        h = fmaf(h, fexp2(Ac * sd[c]), q[c * 16]);
    }
}

__global__ __launch_bounds__(256) void scan_phaseC(
    const float* __restrict__ xp, const float* __restrict__ dl,
    const float* __restrict__ A_log, const float* __restrict__ B_mat,
    const float* __restrict__ C_mat, const float* __restrict__ D_vec,
    const unsigned short* __restrict__ gate, const float* __restrict__ hst,
    unsigned short* __restrict__ z)
{
    const int ch = blockIdx.x * 256 + threadIdx.x;
    const int c = blockIdx.y;
    const int d = ch & 2047, b = ch >> 11;
    float Ac[16], Bv[16], Cv[16], h[16];
    #pragma unroll
    for (int s = 0; s < 16; ++s) {
        Ac[s] = -fexp2(A_log[d * 16 + s] * LOG2E) * LOG2E;
        Bv[s] = B_mat[d * 16 + s];
        Cv[s] = C_mat[s];
        h[s] = hst[((size_t)ch * NC + c) * 16 + s];
    }
    const float Dv = D_vec[d];
    size_t idx = ((size_t)b * 1024 + (size_t)c * CL) * 2048 + d;
    for (int t = 0; t < CL; ++t, idx += 2048) {
        const float xt = xp[idx], dt = dl[idx];
        const float xdt = xt * dt;
        float y = 0.0f;
        #pragma unroll
        for (int s = 0; s < 16; ++s) {
            h[s] = fmaf(h[s], fexp2(Ac[s] * dt), xdt * Bv[s]);
            y = fmaf(h[s], Cv[s], y);
        }
        const float g = bf2f(gate[idx]);
        z[idx] = f2bf(g * (y + xt * Dv));
    }
}

// ---------------------------------------------------------------------------
extern "C" void kernel_launch(void* const* d_in, const int* in_sizes, int n_in,
                              void* d_out, int out_size, void* d_ws, size_t ws_size,
                              hipStream_t stream) {
    const float* x      = (const float*)d_in[0];
    const float* W_in   = (const float*)d_in[1];
    const float* b_in   = (const float*)d_in[2];
    const float* W_gate = (const float*)d_in[3];
    const float* b_gate = (const float*)d_in[4];
    const float* W_out  = (const float*)d_in[5];
    const float* b_out  = (const float*)d_in[6];
    const float* A_log  = (const float*)d_in[7];
    const float* B_mat  = (const float*)d_in[8];
    const float* C_mat  = (const float*)d_in[9];
    const float* D_vec  = (const float*)d_in[10];
    float* out = (float*)d_out;

    float* fws = (float*)d_ws;
    float* xproj = fws;                         //  4,194,304 f32
    float* delta = xproj + 4194304;             //  4,194,304 f32
    float* Q     = delta + 4194304;             //  2,097,152 f32
    float* hst   = Q + 2097152;                 //  2,097,152 f32
    float* sumdt = hst + 2097152;               //    131,072 f32
    unsigned short* us = (unsigned short*)(sumdt + 131072);
    unsigned short* gate  = us;                 //  4,194,304 bf16
    unsigned short* z     = gate + 4194304;     //  4,194,304 bf16
    unsigned short* x_bf  = z + 4194304;        //  2,097,152 bf16
    unsigned short* wg_bf = x_bf + 2097152;     //  2,097,152 bf16
    unsigned short* wi_bf = wg_bf + 2097152;    //  4,194,304 bf16
    unsigned short* wo_bf = wi_bf + 4194304;    //  2,097,152 bf16

    dim3 blk(256);
    cast_to_bf16<<<10240, blk, 0, stream>>>(x, W_gate, W_in, W_out, x_bf, wg_bf, wi_bf, wo_bf);
    // fused: gate = sigmoid(x@Wg^T+bg) -> bf16 ; proj = x@Wi^T+bi -> xproj|relu delta
    gemm_mfma<3, 4><<<dim3(48, 16), blk, 0, stream>>>(
        x_bf, wg_bf, wi_bf, b_gate, b_in, gate, xproj, delta, nullptr, 1024);
    scan_phaseA<<<dim3(16, NC), blk, 0, stream>>>(xproj, delta, A_log, B_mat, Q, sumdt);
    scan_phaseB<<<256, blk, 0, stream>>>(A_log, Q, sumdt, hst);
    scan_phaseC<<<dim3(16, NC), blk, 0, stream>>>(xproj, delta, A_log, B_mat, C_mat, D_vec, gate, hst, z);
    // out = z @ W_out^T + b_out : M=2048, N=1024, K=2048 (64x128 tiles)
    gemm_mfma<2, 2><<<dim3(8, 32), blk, 0, stream>>>(
        z, wo_bf, nullptr, b_out, nullptr, nullptr, nullptr, nullptr, out, 2048);
}